// Round 6
// baseline (290.343 us; speedup 1.0000x reference)
//
#include <hip/hip_runtime.h>
#include <math.h>

#define CC 256
#define NSP 4096
#define L2E 1.44269504088896340736f
#define SH2 (48.0f * L2E)

typedef float f32x2  __attribute__((ext_vector_type(2)));
typedef float f32x4  __attribute__((ext_vector_type(4)));
typedef float f32x16 __attribute__((ext_vector_type(16)));
typedef _Float16 half8 __attribute__((ext_vector_type(8)));
typedef unsigned short u16;
typedef unsigned int   u32;

__device__ __forceinline__ half8 ld_frag(const u16* p) {
    int4 v = *(const int4*)p;
    return __builtin_bit_cast(half8, v);
}
__device__ __forceinline__ u32 pkrtz(float a, float b) {
    return __builtin_bit_cast(u32, __builtin_amdgcn_cvt_pkrtz(a, b));
}
__device__ __forceinline__ u16 f16b(float x) {
    _Float16 h = (_Float16)x;
    return __builtin_bit_cast(u16, h);
}

// ---------------------------------------------------------------------------
// conv_qkv: all three projections in ONE launch, 1280 blocks = 5 waves/SIMD.
// Register-double-buffered x loads (xvA/xvB, static indexing) hide L2 latency
// under the FMA blocks. W reads wave-uniform (scalar cache). Epilogues emit
// the SAME packed layouts verified in R4/R5: K hi/lo f16 (xL2E), Q f16,
// V transposed f16, all frag-major.
//   id <  512: K  (o-tile 16, s-tile 256, 1 s/thread)
//   id < 1024: Q  (same)
//   id >=1024: V  (o-tile 16, s-tile 512, 2 s/thread, 16 KB LDS transpose)
// ---------------------------------------------------------------------------
__global__ __launch_bounds__(256) void conv_qkv(
    const float* __restrict__ in1, const float* __restrict__ in2,
    const float* __restrict__ W1, const float* __restrict__ b1,
    const float* __restrict__ W2, const float* __restrict__ b2,
    const float* __restrict__ W3, const float* __restrict__ b3,
    u16* __restrict__ Khi, u16* __restrict__ Klo,
    u16* __restrict__ Qpk, u16* __restrict__ Vpk)
{
    __shared__ __align__(16) u16 sb16[16 * 512];   // V-path transpose buffer
    const int tid = threadIdx.x;
    const int id  = blockIdx.x;

    if (id < 1024) {
        // -------------------- K / Q --------------------
        const int kind = id >> 9;              // 0 = K, 1 = Q
        const int kid  = id & 511;
        const int ot   = kid >> 5;             // 0..15
        const int stb  = kid & 31;
        const int b    = stb >> 4;
        const int s0   = (stb & 15) * 256;
        const int o0   = ot * 16;
        const float* W    = kind ? W2 : W1;
        const float* bias = kind ? b2 : b1;

        const int sg = s0 + tid;
        const float* xp = in1 + (size_t)b * CC * NSP + sg;

        float acc[16];
#pragma unroll
        for (int oo = 0; oo < 16; ++oo) acc[oo] = bias[o0 + oo];

        float xvA[8], xvB[8];
        auto load8 = [&](float* xv, int c8) {
#pragma unroll
            for (int cc = 0; cc < 8; ++cc)
                xv[cc] = xp[(size_t)(c8 * 8 + cc) * NSP];
        };
        auto fma8 = [&](const float* xv, int c8) {
#pragma unroll
            for (int oo = 0; oo < 16; ++oo) {
                const f32x4 w0 = *(const f32x4*)&W[(o0 + oo) * CC + c8 * 8];
                const f32x4 w1 = *(const f32x4*)&W[(o0 + oo) * CC + c8 * 8 + 4];
#pragma unroll
                for (int cc = 0; cc < 4; ++cc) {
                    acc[oo] += w0[cc] * xv[cc];
                    acc[oo] += w1[cc] * xv[4 + cc];
                }
            }
        };

        load8(xvA, 0);
        load8(xvB, 1);
        for (int c8 = 0; c8 < 32; c8 += 2) {
            fma8(xvA, c8);
            if (c8 + 2 < 32) load8(xvA, c8 + 2);
            fma8(xvB, c8 + 1);
            if (c8 + 3 < 32) load8(xvB, c8 + 3);
        }

        const float sc = kind ? 1.0f : L2E;
        const int m  = (sg >> 3) & 7;
        const int ri = sg >> 6;
        u16* outA = kind ? Qpk : Khi;
#pragma unroll
        for (int oo = 0; oo < 16; ++oo) {
            const int c    = o0 + oo;
            const int slab = (b * 4 + (c >> 6)) * 64 + (c & 63);
            const float av = acc[oo] * sc;
            const _Float16 hf = (_Float16)av;          // RNE
            u32 h  = (u32)__builtin_bit_cast(u16, hf);
            u32 p0 = h | ((u32)__shfl_xor((int)h, 1) << 16);
            u32 p2 = (u32)__shfl_xor((int)p0, 2);
            u32 p4 = (u32)__shfl_xor((int)p0, 4);
            u32 p6 = (u32)__shfl_xor((int)p0, 6);
            if (!(tid & 7))
                *(int4*)(outA + ((size_t)slab * 512 + m * 64 + ri) * 8)
                    = make_int4((int)p0, (int)p2, (int)p4, (int)p6);
            if (kind == 0) {
                const float lo = av - (float)hf;
                u32 hl = (u32)f16b(lo);
                u32 q0 = hl | ((u32)__shfl_xor((int)hl, 1) << 16);
                u32 q2 = (u32)__shfl_xor((int)q0, 2);
                u32 q4 = (u32)__shfl_xor((int)q0, 4);
                u32 q6 = (u32)__shfl_xor((int)q0, 6);
                if (!(tid & 7))
                    *(int4*)(Klo + ((size_t)slab * 512 + m * 64 + ri) * 8)
                        = make_int4((int)q0, (int)q2, (int)q4, (int)q6);
            }
        }
    } else {
        // -------------------- V (transposed pack) --------------------
        const int vid = id - 1024;
        const int ot  = vid >> 4;              // 0..15
        const int stb = vid & 15;
        const int b   = stb >> 3;
        const int st8 = stb & 7;
        const int s0  = st8 * 512;
        const int o0  = ot * 16;

        const int sg = s0 + tid * 2;
        const float* xp = in2 + (size_t)b * CC * NSP + sg;

        f32x2 acc[16];
#pragma unroll
        for (int oo = 0; oo < 16; ++oo) {
            const float bv = b3[o0 + oo];
            acc[oo] = (f32x2){bv, bv};
        }

        f32x2 xvA[8], xvB[8];
        auto load8v = [&](f32x2* xv, int c8) {
#pragma unroll
            for (int cc = 0; cc < 8; ++cc)
                xv[cc] = *(const f32x2*)&xp[(size_t)(c8 * 8 + cc) * NSP];
        };
        auto fma8v = [&](const f32x2* xv, int c8) {
#pragma unroll
            for (int oo = 0; oo < 16; ++oo) {
                const f32x4 w0 = *(const f32x4*)&W3[(o0 + oo) * CC + c8 * 8];
                const f32x4 w1 = *(const f32x4*)&W3[(o0 + oo) * CC + c8 * 8 + 4];
#pragma unroll
                for (int cc = 0; cc < 4; ++cc) {
                    acc[oo] += w0[cc] * xv[cc];
                    acc[oo] += w1[cc] * xv[4 + cc];
                }
            }
        };

        load8v(xvA, 0);
        load8v(xvB, 1);
        for (int c8 = 0; c8 < 32; c8 += 2) {
            fma8v(xvA, c8);
            if (c8 + 2 < 32) load8v(xvA, c8 + 2);
            fma8v(xvB, c8 + 1);
            if (c8 + 3 < 32) load8v(xvB, c8 + 3);
        }

#pragma unroll
        for (int oo = 0; oo < 16; ++oo)
            *(u32*)&sb16[oo * 512 + tid * 2]
                = (u32)f16b(acc[oo][0]) | ((u32)f16b(acc[oo][1]) << 16);
        __syncthreads();
#pragma unroll
        for (int i = 0; i < 4; ++i) {
            const int task = tid + 256 * i;
            const int oo = task >> 6, f = task & 63;
            u16 hq[8];
#pragma unroll
            for (int q = 0; q < 8; ++q) hq[q] = sb16[oo * 512 + q * 64 + f];
            const int c    = o0 + oo;
            const int slab = (b * 4 + (c >> 6)) * 64 + (c & 63);
            *(int4*)(Vpk + ((size_t)slab * 512 + st8 * 64 + f) * 8) = make_int4(
                (int)((u32)hq[0] | ((u32)hq[1] << 16)), (int)((u32)hq[2] | ((u32)hq[3] << 16)),
                (int)((u32)hq[4] | ((u32)hq[5] << 16)), (int)((u32)hq[6] | ((u32)hq[7] << 16)));
        }
    }
}

// ---------------------------------------------------------------------------
// flash3 (verbatim, verified): no LDS, no barriers. S^T = Q*K^T (32x32x16 f16,
// K hi/lo in regs, C-init = -48*log2e), P = exp2(S'), in-register P->A-frag
// via cvt_pkrtz + shfl_xor(32) + half-select, O += P*V.
// grid 512: bh = id&7 (XCD-pinned), tb = (id>>3)>>2, qq = (id>>3)&3.
// ---------------------------------------------------------------------------
__global__ __launch_bounds__(256, 2) void flash3(
    const u16* __restrict__ Khi, const u16* __restrict__ Klo,
    const u16* __restrict__ Qpk, const u16* __restrict__ Vpk,
    float* __restrict__ Opart, float* __restrict__ zpart)
{
    const int tid = threadIdx.x;
    const int w = tid >> 6, l = tid & 63;
    const int h = l >> 5, ln = l & 31;
    const int id = blockIdx.x;
    const int bh = id & 7, rest = id >> 3;
    const int tb = rest >> 2, qq = rest & 3;
    const int b = bh >> 2, hd = bh & 3;
    const int t = tb * 4 + w;

    const u16* Kh = Khi + (size_t)(bh * 64 + t) * 4096;
    const u16* Kl = Klo + (size_t)(bh * 64 + t) * 4096;

    half8 kf_h[2][4], kf_l[2][4];
#pragma unroll
    for (int rt = 0; rt < 2; ++rt)
#pragma unroll
        for (int ks = 0; ks < 4; ++ks) {
            const int cix = ((ks * 2 + h) * 64 + rt * 32 + ln) * 8;
            kf_h[rt][ks] = ld_frag(Kh + cix);
            kf_l[rt][ks] = ld_frag(Kl + cix);
        }

    f32x16 oacc[2][2];
#pragma unroll
    for (int rt = 0; rt < 2; ++rt)
#pragma unroll
        for (int ft = 0; ft < 2; ++ft)
#pragma unroll
            for (int i = 0; i < 16; ++i) oacc[rt][ft][i] = 0.f;
    float zacc[2] = {0.f, 0.f};

    for (int it = 0; it < 16; ++it) {
        const int tq = qq * 16 + it;
        const u16* Qt = Qpk + (size_t)(bh * 64 + tq) * 4096;
        const u16* Vt = Vpk + (size_t)(bh * 64 + tq) * 4096;
#pragma unroll
        for (int jt = 0; jt < 2; ++jt) {
            half8 qf[4];
#pragma unroll
            for (int ks = 0; ks < 4; ++ks)
                qf[ks] = ld_frag(Qt + ((ks * 2 + h) * 64 + jt * 32 + ln) * 8);

            f32x16 sa[2];
#pragma unroll
            for (int rt = 0; rt < 2; ++rt)
#pragma unroll
                for (int i = 0; i < 16; ++i) sa[rt][i] = -SH2;
#pragma unroll
            for (int ks = 0; ks < 4; ++ks) {
                sa[0] = __builtin_amdgcn_mfma_f32_32x32x16_f16(qf[ks], kf_h[0][ks], sa[0], 0, 0, 0);
                sa[1] = __builtin_amdgcn_mfma_f32_32x32x16_f16(qf[ks], kf_h[1][ks], sa[1], 0, 0, 0);
                sa[0] = __builtin_amdgcn_mfma_f32_32x32x16_f16(qf[ks], kf_l[0][ks], sa[0], 0, 0, 0);
                sa[1] = __builtin_amdgcn_mfma_f32_32x32x16_f16(qf[ks], kf_l[1][ks], sa[1], 0, 0, 0);
            }

            half8 vf[2][2];
#pragma unroll
            for (int js = 0; js < 2; ++js)
#pragma unroll
                for (int ft = 0; ft < 2; ++ft)
                    vf[js][ft] = ld_frag(Vt + (((jt * 2 + js) * 2 + h) * 64 + ft * 32 + ln) * 8);

#pragma unroll
            for (int rt = 0; rt < 2; ++rt) {
                float p[16]; float zs = 0.f;
#pragma unroll
                for (int i = 0; i < 16; ++i) { p[i] = exp2f(sa[rt][i]); zs += p[i]; }
                zacc[rt] += zs;
                u32 wd[8], sw[8];
#pragma unroll
                for (int i = 0; i < 8; ++i) wd[i] = pkrtz(p[2 * i], p[2 * i + 1]);
#pragma unroll
                for (int i = 0; i < 8; ++i) sw[i] = (u32)__shfl_xor((int)wd[i], 32);
                int4 c0 = make_int4((int)(h ? sw[2] : wd[0]), (int)(h ? sw[3] : wd[1]),
                                    (int)(h ? wd[2] : sw[0]), (int)(h ? wd[3] : sw[1]));
                int4 c1 = make_int4((int)(h ? sw[6] : wd[4]), (int)(h ? sw[7] : wd[5]),
                                    (int)(h ? wd[6] : sw[4]), (int)(h ? wd[7] : sw[5]));
                const half8 pf0 = __builtin_bit_cast(half8, c0);
                const half8 pf1 = __builtin_bit_cast(half8, c1);
                oacc[rt][0] = __builtin_amdgcn_mfma_f32_32x32x16_f16(pf0, vf[0][0], oacc[rt][0], 0, 0, 0);
                oacc[rt][0] = __builtin_amdgcn_mfma_f32_32x32x16_f16(pf1, vf[1][0], oacc[rt][0], 0, 0, 0);
                oacc[rt][1] = __builtin_amdgcn_mfma_f32_32x32x16_f16(pf0, vf[0][1], oacc[rt][1], 0, 0, 0);
                oacc[rt][1] = __builtin_amdgcn_mfma_f32_32x32x16_f16(pf1, vf[1][1], oacc[rt][1], 0, 0, 0);
            }
        }
    }

#pragma unroll
    for (int rt = 0; rt < 2; ++rt) {
        const float z2 = zacc[rt] + __shfl_xor(zacc[rt], 32);
        if (h == 0)
            zpart[((size_t)qq * 8 + bh) * NSP + t * 64 + rt * 32 + ln] = z2;
    }
    const size_t ob = ((size_t)(qq * 2 + b) * CC + hd * 64 + t) * NSP;
#pragma unroll
    for (int rt = 0; rt < 2; ++rt)
#pragma unroll
        for (int ft = 0; ft < 2; ++ft)
#pragma unroll
            for (int reg = 0; reg < 16; ++reg) {
                const int rin = (reg & 3) + 8 * (reg >> 2) + 4 * h;
                Opart[ob + (size_t)(rt * 32 + rin) * 64 + ft * 32 + ln] = oacc[rt][ft][reg];
            }
}

// ---------------------------------------------------------------------------
__global__ __launch_bounds__(256) void reduce_kernel(
    const float* __restrict__ zp, float* __restrict__ coef)
{
    __shared__ float red[256];
    const int tid = threadIdx.x, bh = blockIdx.x;
    float lz = 0.f;
    for (int i = tid; i < 4 * NSP; i += 256) {
        const int qq = i >> 12, r = i & 4095;
        lz += zp[((size_t)qq * 8 + bh) * NSP + r];
    }
    red[tid] = lz; __syncthreads();
    for (int s = 128; s > 0; s >>= 1) {
        if (tid < s) red[tid] += red[tid + s];
        __syncthreads();
    }
    if (tid == 0) coef[bh] = 1.f / red[0];
}

// ---------------------------------------------------------------------------
// presum: Osum = (sum of 4 tq-quarter partials) * coef[bh].  Pure BW.
// ---------------------------------------------------------------------------
__global__ __launch_bounds__(256) void presum(
    const float* __restrict__ Opart, const float* __restrict__ coef,
    float* __restrict__ Osum)
{
    const size_t TEN = (size_t)2 * CC * NSP;
    const size_t i = ((size_t)blockIdx.x * 256 + threadIdx.x) * 4;
    f32x4 v = *(const f32x4*)(Opart + i)
            + *(const f32x4*)(Opart + TEN + i)
            + *(const f32x4*)(Opart + 2 * TEN + i)
            + *(const f32x4*)(Opart + 3 * TEN + i);
    const int c = (int)((i >> 12) & 255), b = (int)(i >> 20);
    v *= coef[b * 4 + (c >> 6)];
    *(f32x4*)(Osum + i) = v;
}

// ---------------------------------------------------------------------------
// conv_out: out = W4 . Osum + b4, f32. o-tile 8, s-tile 256, 1 s/thread.
// grid 1024 blocks = 4 waves/SIMD, register-double-buffered like conv_qkv.
// ---------------------------------------------------------------------------
__global__ __launch_bounds__(256) void conv_out(
    const float* __restrict__ Osum, const float* __restrict__ W4,
    const float* __restrict__ b4, float* __restrict__ out)
{
    const int tid = threadIdx.x;
    const int id  = blockIdx.x;
    const int ot  = id >> 5;               // 0..31
    const int stb = id & 31;
    const int b   = stb >> 4, s0 = (stb & 15) * 256;
    const int o0  = ot * 8;

    const int sg = s0 + tid;
    const float* xp = Osum + (size_t)b * CC * NSP + sg;

    float acc[8];
#pragma unroll
    for (int oo = 0; oo < 8; ++oo) acc[oo] = b4[o0 + oo];

    float xvA[8], xvB[8];
    auto load8 = [&](float* xv, int c8) {
#pragma unroll
        for (int cc = 0; cc < 8; ++cc)
            xv[cc] = xp[(size_t)(c8 * 8 + cc) * NSP];
    };
    auto fma8 = [&](const float* xv, int c8) {
#pragma unroll
        for (int oo = 0; oo < 8; ++oo) {
            const f32x4 w0 = *(const f32x4*)&W4[(o0 + oo) * CC + c8 * 8];
            const f32x4 w1 = *(const f32x4*)&W4[(o0 + oo) * CC + c8 * 8 + 4];
#pragma unroll
            for (int cc = 0; cc < 4; ++cc) {
                acc[oo] += w0[cc] * xv[cc];
                acc[oo] += w1[cc] * xv[4 + cc];
            }
        }
    };

    load8(xvA, 0);
    load8(xvB, 1);
    for (int c8 = 0; c8 < 32; c8 += 2) {
        fma8(xvA, c8);
        if (c8 + 2 < 32) load8(xvA, c8 + 2);
        fma8(xvB, c8 + 1);
        if (c8 + 3 < 32) load8(xvB, c8 + 3);
    }

#pragma unroll
    for (int oo = 0; oo < 8; ++oo)
        out[((size_t)b * CC + o0 + oo) * NSP + sg] = acc[oo];
}

// ---------------------------------------------------------------------------
extern "C" void kernel_launch(void* const* d_in, const int* in_sizes, int n_in,
                              void* d_out, int out_size, void* d_ws, size_t ws_size,
                              hipStream_t stream)
{
    (void)in_sizes; (void)n_in; (void)out_size; (void)ws_size;
    const float* in1 = (const float*)d_in[0];
    const float* in2 = (const float*)d_in[1];
    const float* W1 = (const float*)d_in[2]; const float* b1 = (const float*)d_in[3];
    const float* W2 = (const float*)d_in[4]; const float* b2 = (const float*)d_in[5];
    const float* W3 = (const float*)d_in[6]; const float* b3 = (const float*)d_in[7];
    const float* W4 = (const float*)d_in[8]; const float* b4 = (const float*)d_in[9];
    float* out = (float*)d_out;

    const size_t TEN = (size_t)2 * CC * NSP;          // 2,097,152 elements
    char* p = (char*)d_ws;
    u16* Khi = (u16*)p; p += TEN * 2;                 // 4 MB each
    u16* Klo = (u16*)p; p += TEN * 2;
    u16* Qpk = (u16*)p; p += TEN * 2;
    u16* Vpk = (u16*)p; p += TEN * 2;
    float* Opart = (float*)p; p += 4 * TEN * 4;       // 32 MB (4 tq-quarter partials)
    float* zpart = (float*)p; p += (size_t)4 * 8 * NSP * 4;
    float* coef  = (float*)p;
    float* Osum  = (float*)Khi;   // alias: Khi/Klo (8 MB) dead after flash3

    conv_qkv<<<dim3(1280), 256, 0, stream>>>(in1, in2, W1, b1, W2, b2, W3, b3,
                                             Khi, Klo, Qpk, Vpk);
    flash3<<<dim3(512), 256, 0, stream>>>(Khi, Klo, Qpk, Vpk, Opart, zpart);
    reduce_kernel<<<dim3(8), 256, 0, stream>>>(zpart, coef);
    presum<<<dim3(2048), 256, 0, stream>>>(Opart, coef, Osum);
    conv_out<<<dim3(1024), 256, 0, stream>>>(Osum, W4, b4, out);
}

// Round 7
// 165.341 us; speedup vs baseline: 1.7560x; 1.7560x over previous
//
#include <hip/hip_runtime.h>
#include <math.h>

#define CC 256
#define NSP 4096
#define L2E 1.44269504088896340736f
#define SH2 (48.0f * L2E)

typedef float f32x2  __attribute__((ext_vector_type(2)));
typedef float f32x4  __attribute__((ext_vector_type(4)));
typedef float f32x16 __attribute__((ext_vector_type(16)));
typedef _Float16 half8 __attribute__((ext_vector_type(8)));
typedef short short8 __attribute__((ext_vector_type(8)));
typedef unsigned short u16;
typedef unsigned int   u32;

__device__ __forceinline__ u16 bf16rne(float x) {
    unsigned u = __float_as_uint(x);
    u += 0x7FFFu + ((u >> 16) & 1u);
    return (u16)(u >> 16);
}
__device__ __forceinline__ half8 ld_frag(const u16* p) {
    int4 v = *(const int4*)p;
    return __builtin_bit_cast(half8, v);
}
__device__ __forceinline__ short8 ld_bfrag(const u16* p) {
    int4 v = *(const int4*)p;
    return __builtin_bit_cast(short8, v);
}
__device__ __forceinline__ u32 pkrtz(float a, float b) {
    return __builtin_bit_cast(u32, __builtin_amdgcn_cvt_pkrtz(a, b));
}
__device__ __forceinline__ u16 f16b(float x) {
    _Float16 h = (_Float16)x;
    return __builtin_bit_cast(u16, h);
}

// ---------------------------------------------------------------------------
// wpack: W (256x256 f32) -> bf16 hi/lo, natural row-major [o][c].
// A-frags are then 16B-contiguous reads from global (L2-hot, flash3 pattern).
// grid (64, 4 slots = W1,W2,W3,W4), 256 thr, 4 elem/thr.
// ---------------------------------------------------------------------------
__global__ __launch_bounds__(256) void wpack(
    const float* __restrict__ W1, const float* __restrict__ W2,
    const float* __restrict__ W3, const float* __restrict__ W4,
    u16* __restrict__ Whi, u16* __restrict__ Wlo)
{
    const int slot = blockIdx.y;
    const float* W = slot == 0 ? W1 : slot == 1 ? W2 : slot == 2 ? W3 : W4;
    const int i = (blockIdx.x * 256 + threadIdx.x) * 4;
    const f32x4 v = *(const f32x4*)(W + i);
    ushort4 h4, l4;
    h4.x = bf16rne(v.x); l4.x = bf16rne(v.x - __uint_as_float((u32)h4.x << 16));
    h4.y = bf16rne(v.y); l4.y = bf16rne(v.y - __uint_as_float((u32)h4.y << 16));
    h4.z = bf16rne(v.z); l4.z = bf16rne(v.z - __uint_as_float((u32)h4.z << 16));
    h4.w = bf16rne(v.w); l4.w = bf16rne(v.w - __uint_as_float((u32)h4.w << 16));
    *(ushort4*)(Whi + slot * 65536 + i) = h4;
    *(ushort4*)(Wlo + slot * 65536 + i) = l4;
}

// ---------------------------------------------------------------------------
// conv_mfma<MODE>: y[o,s] = sum_c W[o,c] x[c,s] + bias[o] as a bf16 hi/lo
// MFMA GEMM (3 products: WhXh + WhXl + WlXh; residual ~1.6e-5).
// Block: 256 thr / 4 waves; tile = 256 o (wave w: o in [w*64,w*64+64)) x 64 s.
// X tile staged once in LDS, transposed [s][c], bf16 hi/lo, XOR-swizzled
// (byte ^= (s&7)<<4) -> conflict-floor ds_read_b128 B-frags (G4, rule 21).
// A-frags (W rows) read directly from pre-packed global.
// MODE 0: x=in1, proj=blockIdx.y (0: K -> f16 hi/lo * L2E; 1: Q -> f16),
//         packed chunk layout = flash3's (verified R4-R6).
// MODE 1: x=in2, V -> f16 natural [c][s] (Vtmp; vpack transposes after).
// MODE 2: x=Opart (4 partials summed * coef[bh] at stage), f32 out.
// grid: (64 s-tiles, nproj, 2 b).
// ---------------------------------------------------------------------------
template<int MODE>
__global__ __launch_bounds__(256) void conv_mfma(
    const float* __restrict__ x,
    const u16* __restrict__ Wpk_hi, const u16* __restrict__ Wpk_lo,
    const float* __restrict__ bias0, const float* __restrict__ bias1,
    u16* __restrict__ pk0, u16* __restrict__ pk1, u16* __restrict__ pk2,
    float* __restrict__ outF, const float* __restrict__ coef)
{
    __shared__ __align__(16) u16 Xhi[64 * 256];   // 32 KB, swizzled [s][c]
    __shared__ __align__(16) u16 Xlo[64 * 256];   // 32 KB

    const int tid = threadIdx.x;
    const int w = tid >> 6, l = tid & 63;
    const int h = l >> 5, ln = l & 31;
    const int st = blockIdx.x;
    const int proj = (MODE == 0) ? blockIdx.y : 0;
    const int b = blockIdx.z;
    const int s0 = st * 64;

    const int slot = (MODE == 0) ? proj : (MODE == 1) ? 2 : 3;
    const u16* Wh = Wpk_hi + slot * 65536;
    const u16* Wl = Wpk_lo + slot * 65536;
    const float* bias = (MODE == 0 && proj == 1) ? bias1 : bias0;

    // ---- stage X tile: wave w covers c = w*64..w*64+63; lane l covers s0+l
    {
        const size_t TEN = (size_t)2 * CC * NSP;
        float cf = 1.0f;
        if constexpr (MODE == 2) cf = coef[b * 4 + w];
        for (int i = 0; i < 8; ++i) {
            const int c0 = w * 64 + i * 8;
            float xv[8];
#pragma unroll
            for (int cc = 0; cc < 8; ++cc) {
                const size_t base = ((size_t)b * CC + c0 + cc) * NSP + s0 + l;
                if constexpr (MODE == 2) {
                    xv[cc] = (x[base] + x[base + TEN] + x[base + 2 * TEN]
                              + x[base + 3 * TEN]) * cf;
                } else {
                    xv[cc] = x[base];
                }
            }
            u32 hw[4], lw[4];
#pragma unroll
            for (int p2 = 0; p2 < 4; ++p2) {
                const u16 h0 = bf16rne(xv[2 * p2]);
                const u16 h1 = bf16rne(xv[2 * p2 + 1]);
                const u16 l0 = bf16rne(xv[2 * p2]     - __uint_as_float((u32)h0 << 16));
                const u16 l1 = bf16rne(xv[2 * p2 + 1] - __uint_as_float((u32)h1 << 16));
                hw[p2] = (u32)h0 | ((u32)h1 << 16);
                lw[p2] = (u32)l0 | ((u32)l1 << 16);
            }
            const int off = ((l * 256 + c0) * 2) ^ ((l & 7) << 4);
            *(uint4*)((char*)Xhi + off) = make_uint4(hw[0], hw[1], hw[2], hw[3]);
            *(uint4*)((char*)Xlo + off) = make_uint4(lw[0], lw[1], lw[2], lw[3]);
        }
    }
    __syncthreads();

    f32x16 acc[2][2];
#pragma unroll
    for (int ti = 0; ti < 2; ++ti)
#pragma unroll
        for (int tj = 0; tj < 2; ++tj)
#pragma unroll
            for (int i = 0; i < 16; ++i) acc[ti][tj][i] = 0.f;

    // ---- k loop: 16 steps of 16 channels; 12 MFMA + 4 LDS b128 + 4 global ----
#pragma unroll 2
    for (int kk = 0; kk < 16; ++kk) {
        const int kc = kk * 16 + h * 8;
        short8 ah[2], al[2];
#pragma unroll
        for (int ti = 0; ti < 2; ++ti) {
            const size_t wrow = (size_t)(w * 64 + ti * 32 + ln) * 256 + kc;
            ah[ti] = ld_bfrag(Wh + wrow);
            al[ti] = ld_bfrag(Wl + wrow);
        }
        short8 bh[2], bl[2];
#pragma unroll
        for (int tj = 0; tj < 2; ++tj) {
            const int srow = tj * 32 + ln;
            const int off = ((srow * 256 + kc) * 2) ^ ((srow & 7) << 4);
            bh[tj] = *(const short8*)((const char*)Xhi + off);
            bl[tj] = *(const short8*)((const char*)Xlo + off);
        }
#pragma unroll
        for (int ti = 0; ti < 2; ++ti)
#pragma unroll
            for (int tj = 0; tj < 2; ++tj) {
                acc[ti][tj] = __builtin_amdgcn_mfma_f32_32x32x16_bf16(ah[ti], bh[tj], acc[ti][tj], 0, 0, 0);
                acc[ti][tj] = __builtin_amdgcn_mfma_f32_32x32x16_bf16(ah[ti], bl[tj], acc[ti][tj], 0, 0, 0);
                acc[ti][tj] = __builtin_amdgcn_mfma_f32_32x32x16_bf16(al[ti], bh[tj], acc[ti][tj], 0, 0, 0);
            }
    }

    // ---- epilogue: D[row=o (reg pattern), col=s (ln)] ----
    if constexpr (MODE == 0) {
        const float sc = proj ? 1.0f : L2E;
#pragma unroll
        for (int ti = 0; ti < 2; ++ti)
#pragma unroll
            for (int reg = 0; reg < 16; ++reg) {
                const int o = w * 64 + ti * 32 + (reg & 3) + 8 * (reg >> 2) + 4 * h;
                const float bv = bias[o];
                const size_t SLB = (size_t)((b * 4 + (o >> 6)) * 64 + (o & 63)) * 4096;
#pragma unroll
                for (int tj = 0; tj < 2; ++tj) {
                    const int sg = s0 + tj * 32 + ln;
                    const float av = (acc[ti][tj][reg] + bv) * sc;
                    const _Float16 hf = (_Float16)av;
                    const size_t ui = SLB + (size_t)(((sg >> 3) & 7) * 64 + (sg >> 6)) * 8 + (sg & 7);
                    if (proj == 0) {
                        pk0[ui] = __builtin_bit_cast(u16, hf);
                        pk1[ui] = f16b(av - (float)hf);
                    } else {
                        pk2[ui] = __builtin_bit_cast(u16, hf);
                    }
                }
            }
    } else if constexpr (MODE == 1) {
#pragma unroll
        for (int ti = 0; ti < 2; ++ti)
#pragma unroll
            for (int reg = 0; reg < 16; ++reg) {
                const int o = w * 64 + ti * 32 + (reg & 3) + 8 * (reg >> 2) + 4 * h;
                const float bv = bias[o];
#pragma unroll
                for (int tj = 0; tj < 2; ++tj) {
                    const int sg = s0 + tj * 32 + ln;
                    pk0[((size_t)b * CC + o) * NSP + sg] = f16b(acc[ti][tj][reg] + bv);
                }
            }
    } else {
#pragma unroll
        for (int ti = 0; ti < 2; ++ti)
#pragma unroll
            for (int reg = 0; reg < 16; ++reg) {
                const int o = w * 64 + ti * 32 + (reg & 3) + 8 * (reg >> 2) + 4 * h;
                const float bv = bias[o];
#pragma unroll
                for (int tj = 0; tj < 2; ++tj) {
                    const int sg = s0 + tj * 32 + ln;
                    outF[((size_t)b * CC + o) * NSP + sg] = acc[ti][tj][reg] + bv;
                }
            }
    }
}

// ---------------------------------------------------------------------------
// vpack: Vtmp f16 natural [b][c][s] -> Vpk frag-major chunks (R5 layout):
// Vpk[(SL*512 + st8*64 + f)*8 + j] = V[c][s = st8*512 + j*64 + f].
// grid 512 (= b*256 + c), 256 thr, 2 chunks/thr. Coalesced both sides.
// ---------------------------------------------------------------------------
__global__ __launch_bounds__(256) void vpack(
    const u16* __restrict__ Vtmp, u16* __restrict__ Vpk)
{
    const int id = blockIdx.x;
    const int b = id >> 8, c = id & 255;
    const u16* src = Vtmp + (size_t)(b * 256 + c) * 4096;
    u16* dst = Vpk + (size_t)((b * 4 + (c >> 6)) * 64 + (c & 63)) * 4096;
#pragma unroll
    for (int i = 0; i < 2; ++i) {
        const int q = threadIdx.x + i * 256;
        const int st8 = q >> 6, f = q & 63;
        u16 hq[8];
#pragma unroll
        for (int j = 0; j < 8; ++j)
            hq[j] = src[st8 * 512 + j * 64 + f];
        *(int4*)(dst + q * 8) = make_int4(
            (int)((u32)hq[0] | ((u32)hq[1] << 16)), (int)((u32)hq[2] | ((u32)hq[3] << 16)),
            (int)((u32)hq[4] | ((u32)hq[5] << 16)), (int)((u32)hq[6] | ((u32)hq[7] << 16)));
    }
}

// ---------------------------------------------------------------------------
// flash3 (verbatim, verified): no LDS, no barriers. S^T = Q*K^T (32x32x16 f16,
// K hi/lo in regs, C-init = -48*log2e), P = exp2(S'), in-register P->A-frag
// via cvt_pkrtz + shfl_xor(32) + half-select, O += P*V.
// grid 512: bh = id&7 (XCD-pinned), tb = (id>>3)>>2, qq = (id>>3)&3.
// ---------------------------------------------------------------------------
__global__ __launch_bounds__(256, 2) void flash3(
    const u16* __restrict__ Khi, const u16* __restrict__ Klo,
    const u16* __restrict__ Qpk, const u16* __restrict__ Vpk,
    float* __restrict__ Opart, float* __restrict__ zpart)
{
    const int tid = threadIdx.x;
    const int w = tid >> 6, l = tid & 63;
    const int h = l >> 5, ln = l & 31;
    const int id = blockIdx.x;
    const int bh = id & 7, rest = id >> 3;
    const int tb = rest >> 2, qq = rest & 3;
    const int b = bh >> 2, hd = bh & 3;
    const int t = tb * 4 + w;

    const u16* Kh = Khi + (size_t)(bh * 64 + t) * 4096;
    const u16* Kl = Klo + (size_t)(bh * 64 + t) * 4096;

    half8 kf_h[2][4], kf_l[2][4];
#pragma unroll
    for (int rt = 0; rt < 2; ++rt)
#pragma unroll
        for (int ks = 0; ks < 4; ++ks) {
            const int cix = ((ks * 2 + h) * 64 + rt * 32 + ln) * 8;
            kf_h[rt][ks] = ld_frag(Kh + cix);
            kf_l[rt][ks] = ld_frag(Kl + cix);
        }

    f32x16 oacc[2][2];
#pragma unroll
    for (int rt = 0; rt < 2; ++rt)
#pragma unroll
        for (int ft = 0; ft < 2; ++ft)
#pragma unroll
            for (int i = 0; i < 16; ++i) oacc[rt][ft][i] = 0.f;
    float zacc[2] = {0.f, 0.f};

    for (int it = 0; it < 16; ++it) {
        const int tq = qq * 16 + it;
        const u16* Qt = Qpk + (size_t)(bh * 64 + tq) * 4096;
        const u16* Vt = Vpk + (size_t)(bh * 64 + tq) * 4096;
#pragma unroll
        for (int jt = 0; jt < 2; ++jt) {
            half8 qf[4];
#pragma unroll
            for (int ks = 0; ks < 4; ++ks)
                qf[ks] = ld_frag(Qt + ((ks * 2 + h) * 64 + jt * 32 + ln) * 8);

            f32x16 sa[2];
#pragma unroll
            for (int rt = 0; rt < 2; ++rt)
#pragma unroll
                for (int i = 0; i < 16; ++i) sa[rt][i] = -SH2;
#pragma unroll
            for (int ks = 0; ks < 4; ++ks) {
                sa[0] = __builtin_amdgcn_mfma_f32_32x32x16_f16(qf[ks], kf_h[0][ks], sa[0], 0, 0, 0);
                sa[1] = __builtin_amdgcn_mfma_f32_32x32x16_f16(qf[ks], kf_h[1][ks], sa[1], 0, 0, 0);
                sa[0] = __builtin_amdgcn_mfma_f32_32x32x16_f16(qf[ks], kf_l[0][ks], sa[0], 0, 0, 0);
                sa[1] = __builtin_amdgcn_mfma_f32_32x32x16_f16(qf[ks], kf_l[1][ks], sa[1], 0, 0, 0);
            }

            half8 vf[2][2];
#pragma unroll
            for (int js = 0; js < 2; ++js)
#pragma unroll
                for (int ft = 0; ft < 2; ++ft)
                    vf[js][ft] = ld_frag(Vt + (((jt * 2 + js) * 2 + h) * 64 + ft * 32 + ln) * 8);

#pragma unroll
            for (int rt = 0; rt < 2; ++rt) {
                float p[16]; float zs = 0.f;
#pragma unroll
                for (int i = 0; i < 16; ++i) { p[i] = exp2f(sa[rt][i]); zs += p[i]; }
                zacc[rt] += zs;
                u32 wd[8], sw[8];
#pragma unroll
                for (int i = 0; i < 8; ++i) wd[i] = pkrtz(p[2 * i], p[2 * i + 1]);
#pragma unroll
                for (int i = 0; i < 8; ++i) sw[i] = (u32)__shfl_xor((int)wd[i], 32);
                int4 c0 = make_int4((int)(h ? sw[2] : wd[0]), (int)(h ? sw[3] : wd[1]),
                                    (int)(h ? wd[2] : sw[0]), (int)(h ? wd[3] : sw[1]));
                int4 c1 = make_int4((int)(h ? sw[6] : wd[4]), (int)(h ? sw[7] : wd[5]),
                                    (int)(h ? wd[6] : sw[4]), (int)(h ? wd[7] : sw[5]));
                const half8 pf0 = __builtin_bit_cast(half8, c0);
                const half8 pf1 = __builtin_bit_cast(half8, c1);
                oacc[rt][0] = __builtin_amdgcn_mfma_f32_32x32x16_f16(pf0, vf[0][0], oacc[rt][0], 0, 0, 0);
                oacc[rt][0] = __builtin_amdgcn_mfma_f32_32x32x16_f16(pf1, vf[1][0], oacc[rt][0], 0, 0, 0);
                oacc[rt][1] = __builtin_amdgcn_mfma_f32_32x32x16_f16(pf0, vf[0][1], oacc[rt][1], 0, 0, 0);
                oacc[rt][1] = __builtin_amdgcn_mfma_f32_32x32x16_f16(pf1, vf[1][1], oacc[rt][1], 0, 0, 0);
            }
        }
    }

#pragma unroll
    for (int rt = 0; rt < 2; ++rt) {
        const float z2 = zacc[rt] + __shfl_xor(zacc[rt], 32);
        if (h == 0)
            zpart[((size_t)qq * 8 + bh) * NSP + t * 64 + rt * 32 + ln] = z2;
    }
    const size_t ob = ((size_t)(qq * 2 + b) * CC + hd * 64 + t) * NSP;
#pragma unroll
    for (int rt = 0; rt < 2; ++rt)
#pragma unroll
        for (int ft = 0; ft < 2; ++ft)
#pragma unroll
            for (int reg = 0; reg < 16; ++reg) {
                const int rin = (reg & 3) + 8 * (reg >> 2) + 4 * h;
                Opart[ob + (size_t)(rt * 32 + rin) * 64 + ft * 32 + ln] = oacc[rt][ft][reg];
            }
}

// ---------------------------------------------------------------------------
__global__ __launch_bounds__(256) void reduce_kernel(
    const float* __restrict__ zp, float* __restrict__ coef)
{
    __shared__ float red[256];
    const int tid = threadIdx.x, bh = blockIdx.x;
    float lz = 0.f;
    for (int i = tid; i < 4 * NSP; i += 256) {
        const int qq = i >> 12, r = i & 4095;
        lz += zp[((size_t)qq * 8 + bh) * NSP + r];
    }
    red[tid] = lz; __syncthreads();
    for (int s = 128; s > 0; s >>= 1) {
        if (tid < s) red[tid] += red[tid + s];
        __syncthreads();
    }
    if (tid == 0) coef[bh] = 1.f / red[0];
}

// ---------------------------------------------------------------------------
extern "C" void kernel_launch(void* const* d_in, const int* in_sizes, int n_in,
                              void* d_out, int out_size, void* d_ws, size_t ws_size,
                              hipStream_t stream)
{
    (void)in_sizes; (void)n_in; (void)out_size; (void)ws_size;
    const float* in1 = (const float*)d_in[0];
    const float* in2 = (const float*)d_in[1];
    const float* W1 = (const float*)d_in[2]; const float* b1 = (const float*)d_in[3];
    const float* W2 = (const float*)d_in[4]; const float* b2 = (const float*)d_in[5];
    const float* W3 = (const float*)d_in[6]; const float* b3 = (const float*)d_in[7];
    const float* W4 = (const float*)d_in[8]; const float* b4 = (const float*)d_in[9];
    float* out = (float*)d_out;

    const size_t TEN = (size_t)2 * CC * NSP;          // 2,097,152 elements
    char* p = (char*)d_ws;
    u16* Khi = (u16*)p; p += TEN * 2;                 // 4 MB each
    u16* Klo = (u16*)p; p += TEN * 2;
    u16* Qpk = (u16*)p; p += TEN * 2;
    u16* Vpk = (u16*)p; p += TEN * 2;
    u16* Wph = (u16*)p; p += 4 * 65536 * 2;           // 512 KB
    u16* Wpl = (u16*)p; p += 4 * 65536 * 2;           // 512 KB
    float* Opart = (float*)p; p += 4 * TEN * 4;       // 32 MB
    float* zpart = (float*)p; p += (size_t)4 * 8 * NSP * 4;
    float* coef  = (float*)p;
    u16* Vtmp = (u16*)Opart;   // alias: dead before flash3 writes Opart

    wpack<<<dim3(64, 4), 256, 0, stream>>>(W1, W2, W3, W4, Wph, Wpl);
    conv_mfma<0><<<dim3(64, 2, 2), 256, 0, stream>>>(
        in1, Wph, Wpl, b1, b2, Khi, Klo, Qpk, nullptr, nullptr);
    conv_mfma<1><<<dim3(64, 1, 2), 256, 0, stream>>>(
        in2, Wph, Wpl, b3, nullptr, Vtmp, nullptr, nullptr, nullptr, nullptr);
    vpack<<<dim3(512), 256, 0, stream>>>(Vtmp, Vpk);
    flash3<<<dim3(512), 256, 0, stream>>>(Khi, Klo, Qpk, Vpk, Opart, zpart);
    reduce_kernel<<<dim3(8), 256, 0, stream>>>(zpart, coef);
    conv_mfma<2><<<dim3(64, 1, 2), 256, 0, stream>>>(
        Opart, Wph, Wpl, b4, nullptr, nullptr, nullptr, nullptr, out, coef);
}